// Round 1
// baseline (665.433 us; speedup 1.0000x reference)
//
#include <hip/hip_runtime.h>
#include <hip/hip_bf16.h>

#define N 8192
#define C 256
#define NCLS 1000

typedef __bf16 bf16x8 __attribute__((ext_vector_type(8)));
typedef float floatx4 __attribute__((ext_vector_type(4)));

__device__ __forceinline__ void gload_lds16(const void* g, void* l) {
    __builtin_amdgcn_global_load_lds(
        (const __attribute__((address_space(1))) void*)g,
        (__attribute__((address_space(3))) void*)l, 16, 0, 0);
}

__device__ __forceinline__ unsigned short f2bf(float x) {
    union { float f; unsigned int u; } a; a.f = x;
    unsigned int u = a.u;
    unsigned int r = (u + 0x7fffu + ((u >> 16) & 1u)) >> 16;  // RNE
    return (unsigned short)r;
}

// --- 1. row L2-normalize + cast to bf16 ------------------------------------
__global__ __launch_bounds__(256) void k_norm(const float* __restrict__ f,
                                              unsigned short* __restrict__ fnb) {
    int wid = threadIdx.x >> 6, lane = threadIdx.x & 63;
    int row = blockIdx.x * 4 + wid;
    const float4* fr = (const float4*)(f + (size_t)row * C);
    float4 v = fr[lane];
    float ss = v.x * v.x + v.y * v.y + v.z * v.z + v.w * v.w;
    #pragma unroll
    for (int m = 1; m < 64; m <<= 1) ss += __shfl_xor(ss, m, 64);
    float scale = 1.0f / fmaxf(sqrtf(ss), 1e-8f);
    ushort4 o;
    o.x = f2bf(v.x * scale); o.y = f2bf(v.y * scale);
    o.z = f2bf(v.z * scale); o.w = f2bf(v.w * scale);
    ((ushort4*)(fnb + (size_t)row * C))[lane] = o;
}

// --- 2. class histogram (single block) -------------------------------------
__global__ __launch_bounds__(1024) void k_hist(const int* __restrict__ lab,
                                               int* __restrict__ cnt) {
    __shared__ int bins[NCLS];
    for (int i = threadIdx.x; i < NCLS; i += 1024) bins[i] = 0;
    __syncthreads();
    for (int i = threadIdx.x; i < N; i += 1024) atomicAdd(&bins[lab[i]], 1);
    __syncthreads();
    for (int i = threadIdx.x; i < NCLS; i += 1024) cnt[i] = bins[i];
}

// --- 3. fused GEMM + logits/perfect write + per-row S,P accumulation -------
__global__ __launch_bounds__(256) void k_gemm(
    const unsigned short* __restrict__ fnb, const int* __restrict__ lab,
    float* __restrict__ logits, float* __restrict__ perfect,
    float* __restrict__ Ssum, float* __restrict__ Psum) {
    __shared__ __align__(16) unsigned short As[128 * 32];
    __shared__ __align__(16) unsigned short Bs[128 * 32];
    __shared__ int Lr[128], Lc[128];

    const int t = threadIdx.x;
    const int wid = t >> 6, lane = t & 63;
    const int waveM = wid >> 1, waveN = wid & 1;
    const int quad = lane >> 4, l15 = lane & 15;
    const int rowBase = blockIdx.y * 128;
    const int colBase = blockIdx.x * 128;

    if (t < 128) Lr[t] = lab[rowBase + t];
    else         Lc[t - 128] = lab[colBase + (t - 128)];

    floatx4 acc[4][4] = {};

    // staging: thread t loads 16B = 8 bf16 ; row = p*64 + wid*16 + lane/4
    const int srow = wid * 16 + (lane >> 2);
    const int scol = (lane & 3) * 8;
    const unsigned short* gA = fnb + (size_t)(rowBase + srow) * C + scol;
    const unsigned short* gB = fnb + (size_t)(colBase + srow) * C + scol;
    char* asb = (char*)As + wid * 1024;
    char* bsb = (char*)Bs + wid * 1024;

    for (int kb = 0; kb < C; kb += 32) {
        __syncthreads();
        gload_lds16(gA + kb,           asb);
        gload_lds16(gA + kb + 64 * C,  asb + 4096);
        gload_lds16(gB + kb,           bsb);
        gload_lds16(gB + kb + 64 * C,  bsb + 4096);
        __syncthreads();
        bf16x8 a[4], b[4];
        #pragma unroll
        for (int i = 0; i < 4; ++i) {
            a[i] = *(const bf16x8*)&As[(waveM * 64 + i * 16 + l15) * 32 + quad * 8];
            b[i] = *(const bf16x8*)&Bs[(waveN * 64 + i * 16 + l15) * 32 + quad * 8];
        }
        #pragma unroll
        for (int i = 0; i < 4; ++i)
            #pragma unroll
            for (int j = 0; j < 4; ++j)
                acc[i][j] = __builtin_amdgcn_mfma_f32_16x16x32_bf16(a[i], b[j], acc[i][j], 0, 0, 0);
    }

    // epilogue: C/D layout col=lane&15, row=quad*4+reg
    const float invT = 10.0f;
    #pragma unroll
    for (int i = 0; i < 4; ++i) {
        #pragma unroll
        for (int r = 0; r < 4; ++r) {
            int lrow = waveM * 64 + i * 16 + quad * 4 + r;
            int row = rowBase + lrow;
            int labr = Lr[lrow];
            float eSum = 0.f, pSum = 0.f;
            #pragma unroll
            for (int j = 0; j < 4; ++j) {
                int lcol = waveN * 64 + j * 16 + l15;
                int col = colBase + lcol;
                float v = acc[i][j][r] * invT;
                size_t off = (size_t)row * N + col;
                logits[off] = v;
                bool same = (labr == Lc[lcol]);
                perfect[off] = same ? 1.0f : -1.0f;
                if (row != col) {
                    eSum += __expf(v);
                    if (same) pSum += v;
                }
            }
            #pragma unroll
            for (int m = 1; m < 16; m <<= 1) {
                eSum += __shfl_xor(eSum, m, 64);
                pSum += __shfl_xor(pSum, m, 64);
            }
            if (l15 == 0) {
                atomicAdd(&Ssum[row], eSum);
                if (pSum != 0.0f) atomicAdd(&Psum[row], pSum);
            }
        }
    }
}

// --- 4. final loss reduction (single block) --------------------------------
__global__ __launch_bounds__(1024) void k_loss(
    const float* __restrict__ S, const float* __restrict__ P,
    const int* __restrict__ lab, const int* __restrict__ cnt,
    float* __restrict__ out) {
    float sum = 0.f;
    for (int i = threadIdx.x; i < N; i += 1024) {
        float Ki = (float)(cnt[lab[i]] - 1);
        float term = (P[i] - Ki * logf(S[i])) / (Ki + 1e-6f);
        sum += term;
    }
    #pragma unroll
    for (int m = 1; m < 64; m <<= 1) sum += __shfl_xor(sum, m, 64);
    __shared__ float wsum[16];
    int wid = threadIdx.x >> 6, lane = threadIdx.x & 63;
    if (lane == 0) wsum[wid] = sum;
    __syncthreads();
    if (threadIdx.x == 0) {
        float tot = 0.f;
        #pragma unroll
        for (int i = 0; i < 16; ++i) tot += wsum[i];
        out[0] = -tot / (float)N;
    }
}

extern "C" void kernel_launch(void* const* d_in, const int* in_sizes, int n_in,
                              void* d_out, int out_size, void* d_ws, size_t ws_size,
                              hipStream_t stream) {
    const float* f = (const float*)d_in[0];
    const int* lab = (const int*)d_in[1];
    float* out = (float*)d_out;
    float* logits = out + 1;
    float* perfect = out + 1 + (size_t)N * N;

    unsigned short* fnb = (unsigned short*)d_ws;                 // 4 MiB
    float* Ssum = (float*)((char*)d_ws + (size_t)N * C * 2);     // 32 KiB
    float* Psum = Ssum + N;                                      // 32 KiB
    int* cnt = (int*)(Psum + N);                                 // 4 KB

    hipMemsetAsync(Ssum, 0, 2 * N * sizeof(float), stream);
    k_norm<<<N / 4, 256, 0, stream>>>(f, fnb);
    k_hist<<<1, 1024, 0, stream>>>(lab, cnt);
    k_gemm<<<dim3(64, 64), 256, 0, stream>>>(fnb, lab, logits, perfect, Ssum, Psum);
    k_loss<<<1, 1024, 0, stream>>>(Ssum, Psum, lab, cnt, out);
}